// Round 1
// baseline (1056.000 us; speedup 1.0000x reference)
//
#include <hip/hip_runtime.h>
#include <stdint.h>
#include <stddef.h>

#define M_SZ 8192
#define F_DIM 512
#define N_Q 32768

typedef __attribute__((ext_vector_type(4))) float f32x4;
typedef __attribute__((ext_vector_type(8))) __bf16 bf16x8;
typedef __attribute__((ext_vector_type(2))) __bf16 bf16x2;

__device__ __forceinline__ float bits_to_f(unsigned u) {
    union { unsigned u; float f; } v; v.u = u; return v.f;
}
// Pack two floats to bf16 pair (RNE, native cvt). Low 16 = a.
__device__ __forceinline__ unsigned pk_bf16(float a, float b) {
    union { bf16x2 v; unsigned u; } cv;
    cv.v.x = (__bf16)a; cv.v.y = (__bf16)b;
    return cv.u;
}
__device__ __forceinline__ unsigned short f2bf(float x) {
    union { bf16x2 v; unsigned u; } cv;
    cv.v.x = (__bf16)x; cv.v.y = (__bf16)0.0f;
    return (unsigned short)(cv.u & 0xffffu);
}
__device__ __forceinline__ bf16x8 as_bf16x8(uint4 u) {
    union { uint4 a; bf16x8 b; } cv; cv.a = u; return cv.b;
}

// ---------------------------------------------------------------------------
// Kernel 1: row-normalize positions & embeddings; pad to float4.
// ---------------------------------------------------------------------------
__global__ void prep_kernel(const float* __restrict__ pos,
                            const float* __restrict__ emb,
                            float* __restrict__ pn4,
                            float* __restrict__ en4,
                            float* __restrict__ pos4) {
    int i = blockIdx.x * 256 + threadIdx.x;
    if (i >= M_SZ) return;
    float x = pos[i * 3 + 0], y = pos[i * 3 + 1], z = pos[i * 3 + 2];
    float inv = 1.0f / __builtin_amdgcn_sqrtf(x * x + y * y + z * z);
    pn4[i * 4 + 0] = x * inv; pn4[i * 4 + 1] = y * inv;
    pn4[i * 4 + 2] = z * inv; pn4[i * 4 + 3] = 0.0f;
    pos4[i * 4 + 0] = x; pos4[i * 4 + 1] = y;
    pos4[i * 4 + 2] = z; pos4[i * 4 + 3] = 0.0f;
    float ex = emb[i * 3 + 0], ey = emb[i * 3 + 1], ez = emb[i * 3 + 2];
    float einv = 1.0f / __builtin_amdgcn_sqrtf(ex * ex + ey * ey + ez * ez);
    en4[i * 4 + 0] = ex * einv; en4[i * 4 + 1] = ey * einv;
    en4[i * 4 + 2] = ez * einv; en4[i * 4 + 3] = 0.0f;
}

// ---------------------------------------------------------------------------
// Kernel 2: features [8192,512] fp32 -> featT [512,8192] bf16.
// ---------------------------------------------------------------------------
__global__ void transpose_kernel(const float* __restrict__ feat,
                                 unsigned short* __restrict__ featT) {
    __shared__ float tile[64 * 65];
    const int jb = blockIdx.x * 64, fb = blockIdx.y * 64;
    const int t = threadIdx.x;
#pragma unroll
    for (int p = 0; p < 16; ++p) {
        int idx = p * 256 + t;
        int j = idx >> 6, f = idx & 63;
        tile[j * 65 + f] = feat[(size_t)(jb + j) * F_DIM + fb + f];
    }
    __syncthreads();
#pragma unroll
    for (int p = 0; p < 16; ++p) {
        int idx = p * 256 + t;
        int f = idx >> 6, j = idx & 63;
        featT[(size_t)(fb + f) * M_SZ + jb + j] = f2bf(tile[j * 65 + f]);
    }
}

// ---------------------------------------------------------------------------
// Kernel 3: fused softmax(pn@en^T) @ [features | positions] -> memT, npe4.
// v2: BM=32, BN=256 (blockIdx.y f-half), BK=32, 256 threads, grid (256,2)
//   -> 2 independent blocks per CU (2 barrier domains per SIMD) so VALU
//   P-gen of one block overlaps MFMA of the other. P-gen duplicated per
//   f-half (cheap); npe accumulation only in yh==0. B loads same-iter,
//   issued after the (L1-hot) en/ps loads so they hide under P-compute.
// ---------------------------------------------------------------------------
__launch_bounds__(256, 2)
__global__ void build_memory_kernel(const float* __restrict__ pn4,
                                    const float* __restrict__ en4,
                                    const float* __restrict__ pos4,
                                    const unsigned short* __restrict__ featT,
                                    unsigned short* __restrict__ memT,
                                    float* __restrict__ npe4) {
    constexpr int BM = 32, BK = 32, PSTR = BK + 8;  // 40 shorts = 80 B row
    __shared__ unsigned short pbuf[2][BM * PSTR];
    __shared__ f32x4 red4[256];
    __shared__ float lbuf[BM];

    const int t = threadIdx.x;
    const int lane = t & 63, wv = t >> 6;            // 4 waves
    const int col = lane & 15, quad = lane >> 4;
    const int mb = blockIdx.x * BM;
    const int yh = blockIdx.y;                       // f-half: 0 or 1
    const int r = t & 31, jq = t >> 5;               // P-row, j-group (4 each)

    const f32x4 pnr = ((const f32x4*)pn4)[mb + r];
    const f32x4* en = (const f32x4*)en4;
    const f32x4* ps = (const f32x4*)pos4;

    // B pointers: rows yh*256 + wv*64 + n*16 + col of featT, k = quad*8
    const unsigned short* bp[4];
#pragma unroll
    for (int n = 0; n < 4; ++n)
        bp[n] = featT + (size_t)(yh * 256 + wv * 64 + n * 16 + col) * M_SZ + quad * 8;

    f32x4 acc[2][4];
    const f32x4 zero4 = {0.f, 0.f, 0.f, 0.f};
#pragma unroll
    for (int m = 0; m < 2; ++m)
#pragma unroll
        for (int n = 0; n < 4; ++n) acc[m][n] = zero4;
    float nx = 0.f, ny = 0.f, nz = 0.f, lp = 0.f;

    uint4 vb[4];

#define B_COMP(SIDE)                                                         \
    {                                                                        \
        float w_[4];                                                         \
        _Pragma("unroll") for (int i = 0; i < 4; ++i) {                      \
            float s = fmaf(pnr.x, ee[i].x, fmaf(pnr.y, ee[i].y, pnr.z * ee[i].z)); \
            w_[i] = __builtin_amdgcn_exp2f(s * 1.44269504f);                 \
        }                                                                    \
        unsigned u0 = pk_bf16(w_[0], w_[1]), u1 = pk_bf16(w_[2], w_[3]);     \
        float wr0 = bits_to_f(u0 << 16), wr1 = bits_to_f(u0 & 0xffff0000u);  \
        float wr2 = bits_to_f(u1 << 16), wr3 = bits_to_f(u1 & 0xffff0000u);  \
        lp += (wr0 + wr1) + (wr2 + wr3);                                     \
        if (yh == 0) {                                                       \
            nx = fmaf(wr0, pp[0].x, fmaf(wr1, pp[1].x, fmaf(wr2, pp[2].x, fmaf(wr3, pp[3].x, nx)))); \
            ny = fmaf(wr0, pp[0].y, fmaf(wr1, pp[1].y, fmaf(wr2, pp[2].y, fmaf(wr3, pp[3].y, ny)))); \
            nz = fmaf(wr0, pp[0].z, fmaf(wr1, pp[1].z, fmaf(wr2, pp[2].z, fmaf(wr3, pp[3].z, nz)))); \
        }                                                                    \
        *(uint2*)(&pbuf[SIDE][r * PSTR + jq * 4]) = make_uint2(u0, u1);      \
    }

#define B_MFMA(SIDE)                                                         \
    {                                                                        \
        __builtin_amdgcn_s_setprio(1);                                       \
        _Pragma("unroll") for (int m = 0; m < 2; ++m) {                      \
            bf16x8 a = *(const bf16x8*)(&pbuf[SIDE][(m * 16 + col) * PSTR + quad * 8]); \
            _Pragma("unroll") for (int n = 0; n < 4; ++n)                    \
                acc[m][n] = __builtin_amdgcn_mfma_f32_16x16x32_bf16(         \
                    a, as_bf16x8(vb[n]), acc[m][n], 0, 0, 0);                \
        }                                                                    \
        __builtin_amdgcn_s_setprio(0);                                       \
    }

#define B_BODY(SIDE, JNXT)                                                   \
    {                                                                        \
        f32x4 ee[4], pp[4];                                                  \
        _Pragma("unroll") for (int i = 0; i < 4; ++i) {                      \
            ee[i] = en[(JNXT) + jq * 4 + i];                                 \
            pp[i] = ps[(JNXT) + jq * 4 + i];                                 \
        }                                                                    \
        _Pragma("unroll") for (int n = 0; n < 4; ++n) {                      \
            vb[n] = *(const uint4*)(bp[n]);  bp[n] += BK;                    \
        }                                                                    \
        B_COMP(SIDE ^ 1)                                                     \
        B_MFMA(SIDE)                                                         \
        __syncthreads();                                                     \
    }

    // prologue: P(0) -> side 0
    {
        f32x4 ee[4], pp[4];
#pragma unroll
        for (int i = 0; i < 4; ++i) {
            ee[i] = en[jq * 4 + i];
            pp[i] = ps[jq * 4 + i];
        }
        B_COMP(0)
    }
    __syncthreads();

    int jn = BK;
    for (int kt = 0; kt < 254; kt += 2) {
        B_BODY(0, jn) jn += BK;
        B_BODY(1, jn) jn += BK;
    }
    B_BODY(0, jn)   // kt = 254: computes P(255) -> side 1
    {               // kt = 255: last B-block, MFMA side 1
#pragma unroll
        for (int n = 0; n < 4; ++n) vb[n] = *(const uint4*)(bp[n]);
        B_MFMA(1)
    }
#undef B_BODY
#undef B_MFMA
#undef B_COMP

    f32x4 mine = {nx, ny, nz, lp};
    red4[t] = mine;
    __syncthreads();
    if (t < BM) {
        f32x4 s = red4[t];
#pragma unroll
        for (int g = 1; g < 8; ++g) {
            f32x4 o = red4[t + 32 * g];
            s.x += o.x; s.y += o.y; s.z += o.z; s.w += o.w;
        }
        lbuf[t] = s.w;
        if (yh == 0) {
            float inv = 1.0f / s.w;
            float X = s.x * inv, Y = s.y * inv, Z = s.z * inv;
            f32x4 o = {X, Y, Z, X * X + Y * Y + Z * Z};
            ((f32x4*)npe4)[mb + t] = o;
        }
    }
    __syncthreads();

    // memT[f][m] = acc/l (C layout: col=lane&15, row=quad*4+reg)
#pragma unroll
    for (int m = 0; m < 2; ++m) {
        f32x4 l4 = *(const f32x4*)(lbuf + m * 16 + quad * 4);
        f32x4 inv4 = {1.0f / l4.x, 1.0f / l4.y, 1.0f / l4.z, 1.0f / l4.w};
        int mg = mb + m * 16 + quad * 4;
#pragma unroll
        for (int n = 0; n < 4; ++n) {
            int fg = yh * 256 + wv * 64 + n * 16 + col;
            uint2 o;
            o.x = pk_bf16(acc[m][n].x * inv4.x, acc[m][n].y * inv4.y);
            o.y = pk_bf16(acc[m][n].z * inv4.z, acc[m][n].w * inv4.w);
            *(uint2*)(memT + (size_t)fg * M_SZ + mg) = o;
        }
    }
}

// ---------------------------------------------------------------------------
// Kernel 4: fused softmax(-cdist(q, npe)) @ memory.
// v2: BM=64, BN=512, BK=32, 256 threads, grid 512 -> 2 blocks/CU so the
// two barrier domains stagger (VALU of one overlaps MFMA of the other).
// Single vb buffer (same-iter loads, issued after the L1-hot npe loads so
// they hide under the dist/exp phase) keeps regs <= 256/wave for 2 w/SIMD.
// ---------------------------------------------------------------------------
__launch_bounds__(256, 2)
__global__ void query_kernel(const float* __restrict__ qpos,
                             const float* __restrict__ npe4,
                             const unsigned short* __restrict__ memT,
                             float* __restrict__ out) {
    constexpr int BM = 64, BK = 32, PSTR = BK + 8;  // 40
    __shared__ unsigned short pbuf[2][BM * PSTR];   // 2 x 5120 B
    __shared__ float redl[256];
    __shared__ float lbuf[BM];

    const int t = threadIdx.x;
    const int lane = t & 63, wv = t >> 6;           // 4 waves
    const int col = lane & 15, quad = lane >> 4;
    const int qb = blockIdx.x * BM;
    const int r = t & 63, jq = t >> 6;              // P-row, j-group (8 each)

    const float qx = qpos[(size_t)(qb + r) * 3 + 0];
    const float qy = qpos[(size_t)(qb + r) * 3 + 1];
    const float qz = qpos[(size_t)(qb + r) * 3 + 2];
    const float q2 = qx * qx + qy * qy + qz * qz;
    const float m2x = -2.0f * qx, m2y = -2.0f * qy, m2z = -2.0f * qz;

    const f32x4* nsrc = (const f32x4*)npe4;

    // B pointers: wave covers 128 f-cols: rows wv*128 + n*16 + col, k=quad*8
    const unsigned short* bp[8];
#pragma unroll
    for (int n = 0; n < 8; ++n)
        bp[n] = memT + (size_t)(wv * 128 + n * 16 + col) * M_SZ + quad * 8;

    f32x4 acc[4][8];
    const f32x4 zero4 = {0.f, 0.f, 0.f, 0.f};
#pragma unroll
    for (int m = 0; m < 4; ++m)
#pragma unroll
        for (int n = 0; n < 8; ++n) acc[m][n] = zero4;
    float lp = 0.f;

    uint4 vb[8];

#define Q_COMP(SIDE)                                                         \
    {                                                                        \
        unsigned pk4[4];                                                     \
        _Pragma("unroll") for (int i = 0; i < 8; i += 2) {                   \
            float s0 = fmaf(m2x, nn[i].x, fmaf(m2y, nn[i].y, fmaf(m2z, nn[i].z, q2 + nn[i].w))); \
            float s1 = fmaf(m2x, nn[i + 1].x, fmaf(m2y, nn[i + 1].y, fmaf(m2z, nn[i + 1].z, q2 + nn[i + 1].w))); \
            s0 = fmaxf(s0, 1e-12f); s1 = fmaxf(s1, 1e-12f);                  \
            float w0 = __builtin_amdgcn_exp2f(__builtin_amdgcn_sqrtf(s0) * -1.44269504f); \
            float w1 = __builtin_amdgcn_exp2f(__builtin_amdgcn_sqrtf(s1) * -1.44269504f); \
            unsigned u = pk_bf16(w0, w1);                                    \
            lp += bits_to_f(u << 16) + bits_to_f(u & 0xffff0000u);           \
            pk4[i >> 1] = u;                                                 \
        }                                                                    \
        *(uint4*)(&pbuf[SIDE][r * PSTR + jq * 8]) =                          \
            make_uint4(pk4[0], pk4[1], pk4[2], pk4[3]);                      \
    }

#define Q_MFMA(SIDE)                                                         \
    {                                                                        \
        __builtin_amdgcn_s_setprio(1);                                       \
        _Pragma("unroll") for (int m = 0; m < 4; ++m) {                      \
            bf16x8 a = *(const bf16x8*)(&pbuf[SIDE][(m * 16 + col) * PSTR + quad * 8]); \
            _Pragma("unroll") for (int n = 0; n < 8; ++n)                    \
                acc[m][n] = __builtin_amdgcn_mfma_f32_16x16x32_bf16(         \
                    a, as_bf16x8(vb[n]), acc[m][n], 0, 0, 0);                \
        }                                                                    \
        __builtin_amdgcn_s_setprio(0);                                       \
    }

#define Q_BODY(SIDE, JNXT)                                                   \
    {                                                                        \
        f32x4 nn[8];                                                         \
        _Pragma("unroll") for (int i = 0; i < 8; ++i)                        \
            nn[i] = nsrc[(JNXT) + jq * 8 + i];                               \
        _Pragma("unroll") for (int n = 0; n < 8; ++n) {                      \
            vb[n] = *(const uint4*)(bp[n]);  bp[n] += BK;                    \
        }                                                                    \
        Q_COMP(SIDE ^ 1)                                                     \
        Q_MFMA(SIDE)                                                         \
        __syncthreads();                                                     \
    }

    // prologue: P(0) -> side 0
    {
        f32x4 nn[8];
#pragma unroll
        for (int i = 0; i < 8; ++i) nn[i] = nsrc[jq * 8 + i];
        Q_COMP(0)
    }
    __syncthreads();

    int jn = BK;
    for (int kt = 0; kt < 254; kt += 2) {
        Q_BODY(0, jn) jn += BK;
        Q_BODY(1, jn) jn += BK;
    }
    Q_BODY(0, jn)   // kt = 254: computes P(255) -> side 1
    {               // kt = 255
#pragma unroll
        for (int n = 0; n < 8; ++n) vb[n] = *(const uint4*)(bp[n]);
        Q_MFMA(1)
    }
#undef Q_BODY
#undef Q_MFMA
#undef Q_COMP

    redl[t] = lp;
    __syncthreads();
    if (t < BM) lbuf[t] = redl[t] + redl[t + 64] + redl[t + 128] + redl[t + 192];
    __syncthreads();

#pragma unroll
    for (int m = 0; m < 4; ++m) {
        f32x4 l4 = *(const f32x4*)(lbuf + m * 16 + quad * 4);
        f32x4 inv4 = {1.0f / l4.x, 1.0f / l4.y, 1.0f / l4.z, 1.0f / l4.w};
        int qg = qb + m * 16 + quad * 4;
#pragma unroll
        for (int n = 0; n < 8; ++n) {
            int fg = wv * 128 + n * 16 + col;
            out[(size_t)(qg + 0) * F_DIM + fg] = acc[m][n].x * inv4.x;
            out[(size_t)(qg + 1) * F_DIM + fg] = acc[m][n].y * inv4.y;
            out[(size_t)(qg + 2) * F_DIM + fg] = acc[m][n].z * inv4.z;
            out[(size_t)(qg + 3) * F_DIM + fg] = acc[m][n].w * inv4.w;
        }
    }
}

// ---------------------------------------------------------------------------
// Workspace layout (bytes):
//   featT : [0,        8388608)   512x8192 bf16
//   memT  : [8388608, 16777216)   512x8192 bf16
//   npe4  : [16777216,16908288)   8192x4 fp32 (x,y,z,|npe|^2)
//   pn4   : [16908288,17039360)
//   en4   : [17039360,17170432)
//   pos4  : [17170432,17301504)
// ---------------------------------------------------------------------------
extern "C" void kernel_launch(void* const* d_in, const int* in_sizes, int n_in,
                              void* d_out, int out_size, void* d_ws, size_t ws_size,
                              hipStream_t stream) {
    const float* features  = (const float*)d_in[0];
    const float* positions = (const float*)d_in[1];
    const float* qpos      = (const float*)d_in[2];
    const float* pemb      = (const float*)d_in[3];
    float* out = (float*)d_out;
    char* ws = (char*)d_ws;

    unsigned short* featT = (unsigned short*)(ws);
    unsigned short* memT  = (unsigned short*)(ws + 8388608);
    float* npe4 = (float*)(ws + 16777216);
    float* pn4  = (float*)(ws + 16908288);
    float* en4  = (float*)(ws + 17039360);
    float* pos4 = (float*)(ws + 17170432);

    hipLaunchKernelGGL(prep_kernel, dim3(M_SZ / 256), dim3(256), 0, stream,
                       positions, pemb, pn4, en4, pos4);
    hipLaunchKernelGGL(transpose_kernel, dim3(M_SZ / 64, F_DIM / 64), dim3(256), 0, stream,
                       features, featT);
    hipLaunchKernelGGL(build_memory_kernel, dim3(M_SZ / 32, 2), dim3(256), 0, stream,
                       pn4, en4, pos4, featT, memT, npe4);
    hipLaunchKernelGGL(query_kernel, dim3(N_Q / 64), dim3(256), 0, stream,
                       qpos, npe4, memT, out);
}

// Round 5
// 887.447 us; speedup vs baseline: 1.1899x; 1.1899x over previous
//
#include <hip/hip_runtime.h>
#include <stdint.h>
#include <stddef.h>

#define M_SZ 8192
#define F_DIM 512
#define N_Q 32768

typedef __attribute__((ext_vector_type(4))) float f32x4;
typedef __attribute__((ext_vector_type(8))) __bf16 bf16x8;
typedef __attribute__((ext_vector_type(2))) __bf16 bf16x2;

__device__ __forceinline__ float bits_to_f(unsigned u) {
    union { unsigned u; float f; } v; v.u = u; return v.f;
}
// Pack two floats to bf16 pair (RNE, native cvt). Low 16 = a.
__device__ __forceinline__ unsigned pk_bf16(float a, float b) {
    union { bf16x2 v; unsigned u; } cv;
    cv.v.x = (__bf16)a; cv.v.y = (__bf16)b;
    return cv.u;
}
__device__ __forceinline__ unsigned short f2bf(float x) {
    union { bf16x2 v; unsigned u; } cv;
    cv.v.x = (__bf16)x; cv.v.y = (__bf16)0.0f;
    return (unsigned short)(cv.u & 0xffffu);
}
__device__ __forceinline__ bf16x8 as_bf16x8(uint4 u) {
    union { uint4 a; bf16x8 b; } cv; cv.a = u; return cv.b;
}

// ---------------------------------------------------------------------------
// Kernel 1: row-normalize positions & embeddings; pad to float4.
// ---------------------------------------------------------------------------
__global__ void prep_kernel(const float* __restrict__ pos,
                            const float* __restrict__ emb,
                            float* __restrict__ pn4,
                            float* __restrict__ en4,
                            float* __restrict__ pos4) {
    int i = blockIdx.x * 256 + threadIdx.x;
    if (i >= M_SZ) return;
    float x = pos[i * 3 + 0], y = pos[i * 3 + 1], z = pos[i * 3 + 2];
    float inv = 1.0f / __builtin_amdgcn_sqrtf(x * x + y * y + z * z);
    pn4[i * 4 + 0] = x * inv; pn4[i * 4 + 1] = y * inv;
    pn4[i * 4 + 2] = z * inv; pn4[i * 4 + 3] = 0.0f;
    pos4[i * 4 + 0] = x; pos4[i * 4 + 1] = y;
    pos4[i * 4 + 2] = z; pos4[i * 4 + 3] = 0.0f;
    float ex = emb[i * 3 + 0], ey = emb[i * 3 + 1], ez = emb[i * 3 + 2];
    float einv = 1.0f / __builtin_amdgcn_sqrtf(ex * ex + ey * ey + ez * ez);
    en4[i * 4 + 0] = ex * einv; en4[i * 4 + 1] = ey * einv;
    en4[i * 4 + 2] = ez * einv; en4[i * 4 + 3] = 0.0f;
}

// ---------------------------------------------------------------------------
// Kernel 2: features [8192,512] fp32 -> featT [512,8192] bf16.
// ---------------------------------------------------------------------------
__global__ void transpose_kernel(const float* __restrict__ feat,
                                 unsigned short* __restrict__ featT) {
    __shared__ float tile[64 * 65];
    const int jb = blockIdx.x * 64, fb = blockIdx.y * 64;
    const int t = threadIdx.x;
#pragma unroll
    for (int p = 0; p < 16; ++p) {
        int idx = p * 256 + t;
        int j = idx >> 6, f = idx & 63;
        tile[j * 65 + f] = feat[(size_t)(jb + j) * F_DIM + fb + f];
    }
    __syncthreads();
#pragma unroll
    for (int p = 0; p < 16; ++p) {
        int idx = p * 256 + t;
        int f = idx >> 6, j = idx & 63;
        featT[(size_t)(fb + f) * M_SZ + jb + j] = f2bf(tile[j * 65 + f]);
    }
}

// ---------------------------------------------------------------------------
// Kernel 3 (v3): fused softmax(pn@en^T) @ [features | positions].
// BM=128, BN=128, BK=64, 512 thr, grid 256 = (64 mb) x (4 fb).
// Traffic fix: each block reads only 2 MB of featT -> 512 MB total (was 2 GB,
// which ran at the ~6 TB/s cache ceiling). fb = bid&3 so each XCD (round-
// robin dispatch) reuses one 2 MB slice that fits its 4 MB L2.
// P-gen duplicated x4 across fb blocks (cheap); npe store gated to fb==0.
// ---------------------------------------------------------------------------
__launch_bounds__(512, 2)
__global__ void build_memory_kernel(const float* __restrict__ pn4,
                                    const float* __restrict__ en4,
                                    const float* __restrict__ pos4,
                                    const unsigned short* __restrict__ featT,
                                    unsigned short* __restrict__ memT,
                                    float* __restrict__ npe4) {
    constexpr int BM = 128, BK = 64, PSTR = BK + 8;  // 72 shorts = 144 B row
    __shared__ unsigned short pbuf[2][BM * PSTR];
    __shared__ f32x4 red4[512];
    __shared__ float lbuf[BM];

    const int t = threadIdx.x;
    const int lane = t & 63, wv = t >> 6;
    const int col = lane & 15, quad = lane >> 4;
    const int bid = blockIdx.x;
    const int fb = bid & 3;              // f-slice: XCD-affine under round-robin
    const int mb = (bid >> 2) * BM;
    const int r = t & 127, jq = t >> 7;  // P-row, j-group (16 j each)

    const f32x4 pnr = ((const f32x4*)pn4)[mb + r];
    const f32x4* en = (const f32x4*)en4;
    const f32x4* ps = (const f32x4*)pos4;

    const unsigned short* bp =
        featT + (size_t)(fb * 128 + wv * 16 + col) * M_SZ + quad * 8;

    f32x4 acc[8];
    const f32x4 zero4 = {0.f, 0.f, 0.f, 0.f};
#pragma unroll
    for (int m = 0; m < 8; ++m) acc[m] = zero4;
    float nx = 0.f, ny = 0.f, nz = 0.f, lp = 0.f;

    uint4 h0A, h0B, h1v;
    h0A = *(const uint4*)(bp);

#define B_COMP(JB, SIDE)                                                     \
    {                                                                        \
        _Pragma("unroll") for (int hh = 0; hh < 2; ++hh) {                   \
            unsigned us[4];                                                  \
            _Pragma("unroll") for (int i = 0; i < 8; i += 2) {               \
                int j = (JB) + jq * 16 + hh * 8 + i;                         \
                f32x4 e0 = en[j], e1 = en[j + 1];                            \
                f32x4 p0 = ps[j], p1 = ps[j + 1];                            \
                float s0 = fmaf(pnr.x, e0.x, fmaf(pnr.y, e0.y, pnr.z * e0.z)); \
                float s1 = fmaf(pnr.x, e1.x, fmaf(pnr.y, e1.y, pnr.z * e1.z)); \
                float w0 = __builtin_amdgcn_exp2f(s0 * 1.44269504f);         \
                float w1 = __builtin_amdgcn_exp2f(s1 * 1.44269504f);         \
                unsigned u = pk_bf16(w0, w1);                                \
                float w0r = bits_to_f(u << 16), w1r = bits_to_f(u & 0xffff0000u); \
                lp += w0r + w1r;                                             \
                nx = fmaf(w0r, p0.x, fmaf(w1r, p1.x, nx));                   \
                ny = fmaf(w0r, p0.y, fmaf(w1r, p1.y, ny));                   \
                nz = fmaf(w0r, p0.z, fmaf(w1r, p1.z, nz));                   \
                us[i >> 1] = u;                                              \
            }                                                                \
            *(uint4*)(&pbuf[(SIDE)][r * PSTR + jq * 16 + hh * 8]) =          \
                make_uint4(us[0], us[1], us[2], us[3]);                      \
        }                                                                    \
    }

#define B_MFMA(SIDE, VB0, VB1)                                               \
    {                                                                        \
        _Pragma("unroll") for (int m = 0; m < 8; ++m) {                      \
            bf16x8 a = *(const bf16x8*)(&pbuf[(SIDE)][(m * 16 + col) * PSTR + quad * 8]); \
            acc[m] = __builtin_amdgcn_mfma_f32_16x16x32_bf16(                \
                a, as_bf16x8(VB0), acc[m], 0, 0, 0);                         \
        }                                                                    \
        _Pragma("unroll") for (int m = 0; m < 8; ++m) {                      \
            bf16x8 a = *(const bf16x8*)(&pbuf[(SIDE)][(m * 16 + col) * PSTR + 32 + quad * 8]); \
            acc[m] = __builtin_amdgcn_mfma_f32_16x16x32_bf16(                \
                a, as_bf16x8(VB1), acc[m], 0, 0, 0);                         \
        }                                                                    \
    }

#define B_BODY(CURH0, NXTH0, SIDE, JNXT)                                     \
    {                                                                        \
        h1v = *(const uint4*)(bp + 32);                                      \
        NXTH0 = *(const uint4*)(bp + 64);                                    \
        bp += 64;                                                            \
        B_COMP(JNXT, (SIDE) ^ 1)                                             \
        B_MFMA(SIDE, CURH0, h1v)                                             \
        __syncthreads();                                                     \
    }

    B_COMP(0, 0)
    __syncthreads();

    int jn = BK;
    for (int kt = 0; kt < 126; kt += 2) {
        B_BODY(h0A, h0B, 0, jn) jn += BK;
        B_BODY(h0B, h0A, 1, jn) jn += BK;
    }
    B_BODY(h0A, h0B, 0, jn)   // kt = 126: computes P(127) -> side 1
    {                         // kt = 127
        h1v = *(const uint4*)(bp + 32);
        B_MFMA(1, h0B, h1v)
    }
#undef B_BODY
#undef B_MFMA
#undef B_COMP

    f32x4 mine = {nx, ny, nz, lp};
    red4[t] = mine;
    __syncthreads();
    if (t < BM) {
        f32x4 s = red4[t];
#pragma unroll
        for (int g = 1; g < 4; ++g) {
            f32x4 o = red4[t + 128 * g];
            s.x += o.x; s.y += o.y; s.z += o.z; s.w += o.w;
        }
        lbuf[t] = s.w;
        if (fb == 0) {
            float inv = 1.0f / s.w;
            float X = s.x * inv, Y = s.y * inv, Z = s.z * inv;
            f32x4 o = {X, Y, Z, X * X + Y * Y + Z * Z};
            ((f32x4*)npe4)[mb + t] = o;
        }
    }
    __syncthreads();

    // memT[f][m] = acc/l (C layout: col=lane&15, row=quad*4+reg)
    {
        int fg = fb * 128 + wv * 16 + col;
#pragma unroll
        for (int m = 0; m < 8; ++m) {
            f32x4 l4 = *(const f32x4*)(lbuf + m * 16 + quad * 4);
            f32x4 inv4 = {1.0f / l4.x, 1.0f / l4.y, 1.0f / l4.z, 1.0f / l4.w};
            int mg = mb + m * 16 + quad * 4;
            uint2 o;
            o.x = pk_bf16(acc[m].x * inv4.x, acc[m].y * inv4.y);
            o.y = pk_bf16(acc[m].z * inv4.z, acc[m].w * inv4.w);
            *(uint2*)(memT + (size_t)fg * M_SZ + mg) = o;
        }
    }
}

// ---------------------------------------------------------------------------
// Kernel 4 (v3): fused softmax(-cdist(q, npe)) @ memory.
// BM=128, BN=512, BK=64, 512 thr, grid 256 (1 block/CU) — v1's proven shape
// (2 GB traffic, below the ~6.1 TB/s cache ceiling) but with HALF the barrier
// intervals (128 vs 256). Prefetch: next tile's h0-half one iter ahead
// (full-body cover), h1-half issued at body start and covered by the 16-j
// COMP phase. vb = 3x16 VGPR keeps combined regs <= 256 for 2 waves/SIMD.
// ---------------------------------------------------------------------------
__launch_bounds__(512, 2)
__global__ void query_kernel(const float* __restrict__ qpos,
                             const float* __restrict__ npe4,
                             const unsigned short* __restrict__ memT,
                             float* __restrict__ out) {
    constexpr int BM = 128, BK = 64, PSTR = BK + 8;  // 72
    __shared__ unsigned short pbuf[2][BM * PSTR];    // 2 x 18432 B
    __shared__ float redl[512];
    __shared__ float lbuf[BM];

    const int t = threadIdx.x;
    const int lane = t & 63, wv = t >> 6;
    const int col = lane & 15, quad = lane >> 4;
    const int qb = blockIdx.x * BM;
    const int r = t & 127, jq = t >> 7;  // P-row, j-group (16 j each)

    const float qx = qpos[(size_t)(qb + r) * 3 + 0];
    const float qy = qpos[(size_t)(qb + r) * 3 + 1];
    const float qz = qpos[(size_t)(qb + r) * 3 + 2];
    const float q2 = qx * qx + qy * qy + qz * qz;
    const float m2x = -2.0f * qx, m2y = -2.0f * qy, m2z = -2.0f * qz;

    const f32x4* nsrc = (const f32x4*)npe4;

    const unsigned short* bp[4];
#pragma unroll
    for (int n = 0; n < 4; ++n)
        bp[n] = memT + (size_t)(wv * 64 + n * 16 + col) * M_SZ + quad * 8;

    f32x4 acc[8][4];
    const f32x4 zero4 = {0.f, 0.f, 0.f, 0.f};
#pragma unroll
    for (int m = 0; m < 8; ++m)
#pragma unroll
        for (int n = 0; n < 4; ++n) acc[m][n] = zero4;
    float lp = 0.f;

    uint4 h0A[4], h0B[4], h1[4];
#pragma unroll
    for (int n = 0; n < 4; ++n) h0A[n] = *(const uint4*)(bp[n]);

#define Q_COMP(JB, SIDE)                                                     \
    {                                                                        \
        _Pragma("unroll") for (int hh = 0; hh < 2; ++hh) {                   \
            unsigned us[4];                                                  \
            _Pragma("unroll") for (int i = 0; i < 8; i += 2) {               \
                int j = (JB) + jq * 16 + hh * 8 + i;                         \
                f32x4 n0 = nsrc[j], n1 = nsrc[j + 1];                        \
                float s0 = fmaf(m2x, n0.x, fmaf(m2y, n0.y, fmaf(m2z, n0.z, q2 + n0.w))); \
                float s1 = fmaf(m2x, n1.x, fmaf(m2y, n1.y, fmaf(m2z, n1.z, q2 + n1.w))); \
                s0 = fmaxf(s0, 1e-12f); s1 = fmaxf(s1, 1e-12f);              \
                float w0 = __builtin_amdgcn_exp2f(__builtin_amdgcn_sqrtf(s0) * -1.44269504f); \
                float w1 = __builtin_amdgcn_exp2f(__builtin_amdgcn_sqrtf(s1) * -1.44269504f); \
                unsigned u = pk_bf16(w0, w1);                                \
                lp += bits_to_f(u << 16) + bits_to_f(u & 0xffff0000u);       \
                us[i >> 1] = u;                                              \
            }                                                                \
            *(uint4*)(&pbuf[(SIDE)][r * PSTR + jq * 16 + hh * 8]) =          \
                make_uint4(us[0], us[1], us[2], us[3]);                      \
        }                                                                    \
    }

#define Q_MFMA(SIDE, VB0, VB1)                                               \
    {                                                                        \
        _Pragma("unroll") for (int m = 0; m < 8; ++m) {                      \
            bf16x8 a = *(const bf16x8*)(&pbuf[(SIDE)][(m * 16 + col) * PSTR + quad * 8]); \
            _Pragma("unroll") for (int n = 0; n < 4; ++n)                    \
                acc[m][n] = __builtin_amdgcn_mfma_f32_16x16x32_bf16(         \
                    a, as_bf16x8(VB0[n]), acc[m][n], 0, 0, 0);               \
        }                                                                    \
        _Pragma("unroll") for (int m = 0; m < 8; ++m) {                      \
            bf16x8 a = *(const bf16x8*)(&pbuf[(SIDE)][(m * 16 + col) * PSTR + 32 + quad * 8]); \
            _Pragma("unroll") for (int n = 0; n < 4; ++n)                    \
                acc[m][n] = __builtin_amdgcn_mfma_f32_16x16x32_bf16(         \
                    a, as_bf16x8(VB1[n]), acc[m][n], 0, 0, 0);               \
        }                                                                    \
    }

#define Q_BODY(CURH0, NXTH0, SIDE, JNXT)                                     \
    {                                                                        \
        _Pragma("unroll") for (int n = 0; n < 4; ++n)                        \
            h1[n] = *(const uint4*)(bp[n] + 32);                             \
        _Pragma("unroll") for (int n = 0; n < 4; ++n) {                      \
            NXTH0[n] = *(const uint4*)(bp[n] + 64);                          \
            bp[n] += 64;                                                     \
        }                                                                    \
        Q_COMP(JNXT, (SIDE) ^ 1)                                             \
        Q_MFMA(SIDE, CURH0, h1)                                              \
        __syncthreads();                                                     \
    }

    Q_COMP(0, 0)
    __syncthreads();

    int jn = BK;
    for (int kt = 0; kt < 126; kt += 2) {
        Q_BODY(h0A, h0B, 0, jn) jn += BK;
        Q_BODY(h0B, h0A, 1, jn) jn += BK;
    }
    Q_BODY(h0A, h0B, 0, jn)   // kt = 126: computes P(127) -> side 1
    {                         // kt = 127
#pragma unroll
        for (int n = 0; n < 4; ++n) h1[n] = *(const uint4*)(bp[n] + 32);
        Q_MFMA(1, h0B, h1)
    }
#undef Q_BODY
#undef Q_MFMA
#undef Q_COMP

    redl[t] = lp;
    __syncthreads();
    if (t < BM) lbuf[t] = redl[t] + redl[t + 128] + redl[t + 256] + redl[t + 384];
    __syncthreads();

#pragma unroll
    for (int m = 0; m < 8; ++m) {
        f32x4 l4 = *(const f32x4*)(lbuf + m * 16 + quad * 4);
        f32x4 inv4 = {1.0f / l4.x, 1.0f / l4.y, 1.0f / l4.z, 1.0f / l4.w};
        int qg = qb + m * 16 + quad * 4;
#pragma unroll
        for (int n = 0; n < 4; ++n) {
            int fg = wv * 64 + n * 16 + col;
            out[(size_t)(qg + 0) * F_DIM + fg] = acc[m][n].x * inv4.x;
            out[(size_t)(qg + 1) * F_DIM + fg] = acc[m][n].y * inv4.y;
            out[(size_t)(qg + 2) * F_DIM + fg] = acc[m][n].z * inv4.z;
            out[(size_t)(qg + 3) * F_DIM + fg] = acc[m][n].w * inv4.w;
        }
    }
}

// ---------------------------------------------------------------------------
// Workspace layout (bytes):
//   featT : [0,        8388608)   512x8192 bf16
//   memT  : [8388608, 16777216)   512x8192 bf16
//   npe4  : [16777216,16908288)   8192x4 fp32 (x,y,z,|npe|^2)
//   pn4   : [16908288,17039360)
//   en4   : [17039360,17170432)
//   pos4  : [17170432,17301504)
// ---------------------------------------------------------------------------
extern "C" void kernel_launch(void* const* d_in, const int* in_sizes, int n_in,
                              void* d_out, int out_size, void* d_ws, size_t ws_size,
                              hipStream_t stream) {
    const float* features  = (const float*)d_in[0];
    const float* positions = (const float*)d_in[1];
    const float* qpos      = (const float*)d_in[2];
    const float* pemb      = (const float*)d_in[3];
    float* out = (float*)d_out;
    char* ws = (char*)d_ws;

    unsigned short* featT = (unsigned short*)(ws);
    unsigned short* memT  = (unsigned short*)(ws + 8388608);
    float* npe4 = (float*)(ws + 16777216);
    float* pn4  = (float*)(ws + 16908288);
    float* en4  = (float*)(ws + 17039360);
    float* pos4 = (float*)(ws + 17170432);

    hipLaunchKernelGGL(prep_kernel, dim3(M_SZ / 256), dim3(256), 0, stream,
                       positions, pemb, pn4, en4, pos4);
    hipLaunchKernelGGL(transpose_kernel, dim3(M_SZ / 64, F_DIM / 64), dim3(256), 0, stream,
                       features, featT);
    hipLaunchKernelGGL(build_memory_kernel, dim3((M_SZ / 128) * 4), dim3(512), 0, stream,
                       pn4, en4, pos4, featT, memT, npe4);
    hipLaunchKernelGGL(query_kernel, dim3(N_Q / 128), dim3(512), 0, stream,
                       qpos, npe4, memT, out);
}

// Round 6
// 845.179 us; speedup vs baseline: 1.2494x; 1.0500x over previous
//
#include <hip/hip_runtime.h>
#include <stdint.h>
#include <stddef.h>

#define M_SZ 8192
#define F_DIM 512
#define N_Q 32768

typedef __attribute__((ext_vector_type(4))) float f32x4;
typedef __attribute__((ext_vector_type(8))) __bf16 bf16x8;
typedef __attribute__((ext_vector_type(2))) __bf16 bf16x2;

__device__ __forceinline__ float bits_to_f(unsigned u) {
    union { unsigned u; float f; } v; v.u = u; return v.f;
}
// Pack two floats to bf16 pair (RNE, native cvt). Low 16 = a.
__device__ __forceinline__ unsigned pk_bf16(float a, float b) {
    union { bf16x2 v; unsigned u; } cv;
    cv.v.x = (__bf16)a; cv.v.y = (__bf16)b;
    return cv.u;
}
__device__ __forceinline__ unsigned short f2bf(float x) {
    union { bf16x2 v; unsigned u; } cv;
    cv.v.x = (__bf16)x; cv.v.y = (__bf16)0.0f;
    return (unsigned short)(cv.u & 0xffffu);
}
__device__ __forceinline__ bf16x8 as_bf16x8(uint4 u) {
    union { uint4 a; bf16x8 b; } cv; cv.a = u; return cv.b;
}

// K-loop barrier WITHOUT the __syncthreads vmcnt(0) drain: only LDS writes
// (pbuf) need cross-wave visibility -> lgkmcnt(0) per wave + s_barrier.
// In-flight global register loads legally span the barrier (T4); the
// compiler still emits counted vmcnt(N) at each use. sched_barrier pins
// ordering (rule #18).
__device__ __forceinline__ void wg_barrier() {
    asm volatile("s_waitcnt lgkmcnt(0)" ::: "memory");
    __builtin_amdgcn_s_barrier();
    __builtin_amdgcn_sched_barrier(0);
}

// ---------------------------------------------------------------------------
// Kernel 1: row-normalize positions & embeddings; pad to float4.
// ---------------------------------------------------------------------------
__global__ void prep_kernel(const float* __restrict__ pos,
                            const float* __restrict__ emb,
                            float* __restrict__ pn4,
                            float* __restrict__ en4,
                            float* __restrict__ pos4) {
    int i = blockIdx.x * 256 + threadIdx.x;
    if (i >= M_SZ) return;
    float x = pos[i * 3 + 0], y = pos[i * 3 + 1], z = pos[i * 3 + 2];
    float inv = 1.0f / __builtin_amdgcn_sqrtf(x * x + y * y + z * z);
    pn4[i * 4 + 0] = x * inv; pn4[i * 4 + 1] = y * inv;
    pn4[i * 4 + 2] = z * inv; pn4[i * 4 + 3] = 0.0f;
    pos4[i * 4 + 0] = x; pos4[i * 4 + 1] = y;
    pos4[i * 4 + 2] = z; pos4[i * 4 + 3] = 0.0f;
    float ex = emb[i * 3 + 0], ey = emb[i * 3 + 1], ez = emb[i * 3 + 2];
    float einv = 1.0f / __builtin_amdgcn_sqrtf(ex * ex + ey * ey + ez * ez);
    en4[i * 4 + 0] = ex * einv; en4[i * 4 + 1] = ey * einv;
    en4[i * 4 + 2] = ez * einv; en4[i * 4 + 3] = 0.0f;
}

// ---------------------------------------------------------------------------
// Kernel 2: features [8192,512] fp32 -> featT [512,8192] bf16.
// ---------------------------------------------------------------------------
__global__ void transpose_kernel(const float* __restrict__ feat,
                                 unsigned short* __restrict__ featT) {
    __shared__ float tile[64 * 65];
    const int jb = blockIdx.x * 64, fb = blockIdx.y * 64;
    const int t = threadIdx.x;
#pragma unroll
    for (int p = 0; p < 16; ++p) {
        int idx = p * 256 + t;
        int j = idx >> 6, f = idx & 63;
        tile[j * 65 + f] = feat[(size_t)(jb + j) * F_DIM + fb + f];
    }
    __syncthreads();
#pragma unroll
    for (int p = 0; p < 16; ++p) {
        int idx = p * 256 + t;
        int f = idx >> 6, j = idx & 63;
        featT[(size_t)(fb + f) * M_SZ + jb + j] = f2bf(tile[j * 65 + f]);
    }
}

// ---------------------------------------------------------------------------
// Kernel 3 (v4): v3 shape (BM=128, BN=128, BK=64, f-split fb=bid&3) with
// the K-loop __syncthreads replaced by wg_barrier (no vmcnt drain) so the
// featT prefetch stays in flight across the barrier.
// ---------------------------------------------------------------------------
__launch_bounds__(512, 2)
__global__ void build_memory_kernel(const float* __restrict__ pn4,
                                    const float* __restrict__ en4,
                                    const float* __restrict__ pos4,
                                    const unsigned short* __restrict__ featT,
                                    unsigned short* __restrict__ memT,
                                    float* __restrict__ npe4) {
    constexpr int BM = 128, BK = 64, PSTR = BK + 8;  // 72 shorts = 144 B row
    __shared__ unsigned short pbuf[2][BM * PSTR];
    __shared__ f32x4 red4[512];
    __shared__ float lbuf[BM];

    const int t = threadIdx.x;
    const int lane = t & 63, wv = t >> 6;
    const int col = lane & 15, quad = lane >> 4;
    const int bid = blockIdx.x;
    const int fb = bid & 3;              // f-slice: XCD-affine under round-robin
    const int mb = (bid >> 2) * BM;
    const int r = t & 127, jq = t >> 7;  // P-row, j-group (16 j each)

    const f32x4 pnr = ((const f32x4*)pn4)[mb + r];
    const f32x4* en = (const f32x4*)en4;
    const f32x4* ps = (const f32x4*)pos4;

    const unsigned short* bp =
        featT + (size_t)(fb * 128 + wv * 16 + col) * M_SZ + quad * 8;

    f32x4 acc[8];
    const f32x4 zero4 = {0.f, 0.f, 0.f, 0.f};
#pragma unroll
    for (int m = 0; m < 8; ++m) acc[m] = zero4;
    float nx = 0.f, ny = 0.f, nz = 0.f, lp = 0.f;

    uint4 h0A, h0B, h1v;
    h0A = *(const uint4*)(bp);

#define B_COMP(JB, SIDE)                                                     \
    {                                                                        \
        _Pragma("unroll") for (int hh = 0; hh < 2; ++hh) {                   \
            unsigned us[4];                                                  \
            _Pragma("unroll") for (int i = 0; i < 8; i += 2) {               \
                int j = (JB) + jq * 16 + hh * 8 + i;                         \
                f32x4 e0 = en[j], e1 = en[j + 1];                            \
                f32x4 p0 = ps[j], p1 = ps[j + 1];                            \
                float s0 = fmaf(pnr.x, e0.x, fmaf(pnr.y, e0.y, pnr.z * e0.z)); \
                float s1 = fmaf(pnr.x, e1.x, fmaf(pnr.y, e1.y, pnr.z * e1.z)); \
                float w0 = __builtin_amdgcn_exp2f(s0 * 1.44269504f);         \
                float w1 = __builtin_amdgcn_exp2f(s1 * 1.44269504f);         \
                unsigned u = pk_bf16(w0, w1);                                \
                float w0r = bits_to_f(u << 16), w1r = bits_to_f(u & 0xffff0000u); \
                lp += w0r + w1r;                                             \
                nx = fmaf(w0r, p0.x, fmaf(w1r, p1.x, nx));                   \
                ny = fmaf(w0r, p0.y, fmaf(w1r, p1.y, ny));                   \
                nz = fmaf(w0r, p0.z, fmaf(w1r, p1.z, nz));                   \
                us[i >> 1] = u;                                              \
            }                                                                \
            *(uint4*)(&pbuf[(SIDE)][r * PSTR + jq * 16 + hh * 8]) =          \
                make_uint4(us[0], us[1], us[2], us[3]);                      \
        }                                                                    \
    }

#define B_MFMA(SIDE, VB0, VB1)                                               \
    {                                                                        \
        _Pragma("unroll") for (int m = 0; m < 8; ++m) {                      \
            bf16x8 a = *(const bf16x8*)(&pbuf[(SIDE)][(m * 16 + col) * PSTR + quad * 8]); \
            acc[m] = __builtin_amdgcn_mfma_f32_16x16x32_bf16(                \
                a, as_bf16x8(VB0), acc[m], 0, 0, 0);                         \
        }                                                                    \
        _Pragma("unroll") for (int m = 0; m < 8; ++m) {                      \
            bf16x8 a = *(const bf16x8*)(&pbuf[(SIDE)][(m * 16 + col) * PSTR + 32 + quad * 8]); \
            acc[m] = __builtin_amdgcn_mfma_f32_16x16x32_bf16(                \
                a, as_bf16x8(VB1), acc[m], 0, 0, 0);                         \
        }                                                                    \
    }

#define B_BODY(CURH0, NXTH0, SIDE, JNXT)                                     \
    {                                                                        \
        h1v = *(const uint4*)(bp + 32);                                      \
        NXTH0 = *(const uint4*)(bp + 64);                                    \
        bp += 64;                                                            \
        B_COMP(JNXT, (SIDE) ^ 1)                                             \
        B_MFMA(SIDE, CURH0, h1v)                                             \
        wg_barrier();                                                        \
    }

    B_COMP(0, 0)
    wg_barrier();

    int jn = BK;
    for (int kt = 0; kt < 126; kt += 2) {
        B_BODY(h0A, h0B, 0, jn) jn += BK;
        B_BODY(h0B, h0A, 1, jn) jn += BK;
    }
    B_BODY(h0A, h0B, 0, jn)   // kt = 126: computes P(127) -> side 1
    {                         // kt = 127
        h1v = *(const uint4*)(bp + 32);
        B_MFMA(1, h0B, h1v)
    }
#undef B_BODY
#undef B_MFMA
#undef B_COMP

    f32x4 mine = {nx, ny, nz, lp};
    red4[t] = mine;
    __syncthreads();
    if (t < BM) {
        f32x4 s = red4[t];
#pragma unroll
        for (int g = 1; g < 4; ++g) {
            f32x4 o = red4[t + 128 * g];
            s.x += o.x; s.y += o.y; s.z += o.z; s.w += o.w;
        }
        lbuf[t] = s.w;
        if (fb == 0) {
            float inv = 1.0f / s.w;
            float X = s.x * inv, Y = s.y * inv, Z = s.z * inv;
            f32x4 o = {X, Y, Z, X * X + Y * Y + Z * Z};
            ((f32x4*)npe4)[mb + t] = o;
        }
    }
    __syncthreads();

    // memT[f][m] = acc/l (C layout: col=lane&15, row=quad*4+reg)
    {
        int fg = fb * 128 + wv * 16 + col;
#pragma unroll
        for (int m = 0; m < 8; ++m) {
            f32x4 l4 = *(const f32x4*)(lbuf + m * 16 + quad * 4);
            f32x4 inv4 = {1.0f / l4.x, 1.0f / l4.y, 1.0f / l4.z, 1.0f / l4.w};
            int mg = mb + m * 16 + quad * 4;
            uint2 o;
            o.x = pk_bf16(acc[m].x * inv4.x, acc[m].y * inv4.y);
            o.y = pk_bf16(acc[m].z * inv4.z, acc[m].w * inv4.w);
            *(uint2*)(memT + (size_t)fg * M_SZ + mg) = o;
        }
    }
}

// ---------------------------------------------------------------------------
// Kernel 4 (v4): v1's proven shape (BM=128, BN=512, BK=32, 512 thr, one-
// iter-ahead vbA/vbB prefetch) with the K-loop __syncthreads replaced by
// wg_barrier — the prefetch now truly spans the barrier instead of being
// drained by the implicit vmcnt(0).
// ---------------------------------------------------------------------------
__launch_bounds__(512, 2)
__global__ void query_kernel(const float* __restrict__ qpos,
                             const float* __restrict__ npe4,
                             const unsigned short* __restrict__ memT,
                             float* __restrict__ out) {
    constexpr int BM = 128, BK = 32, PSTR = BK + 8;  // 40
    __shared__ unsigned short pbuf[2][BM * PSTR];    // 2 x 10240 B
    __shared__ float redl[512];
    __shared__ float lbuf[BM];

    const int t = threadIdx.x;
    const int lane = t & 63, wv = t >> 6;
    const int col = lane & 15, quad = lane >> 4;
    const int qb = blockIdx.x * BM;
    const int r = t & 127, jq = t >> 7;  // P-row, j-group (8 each)

    const float qx = qpos[(size_t)(qb + r) * 3 + 0];
    const float qy = qpos[(size_t)(qb + r) * 3 + 1];
    const float qz = qpos[(size_t)(qb + r) * 3 + 2];
    const float q2 = qx * qx + qy * qy + qz * qz;
    const float m2x = -2.0f * qx, m2y = -2.0f * qy, m2z = -2.0f * qz;

    const f32x4* nsrc = (const f32x4*)npe4;

    const unsigned short* bp[4];
#pragma unroll
    for (int n = 0; n < 4; ++n)
        bp[n] = memT + (size_t)(wv * 64 + n * 16 + col) * M_SZ + quad * 8;

    f32x4 acc[8][4];
    const f32x4 zero4 = {0.f, 0.f, 0.f, 0.f};
#pragma unroll
    for (int m = 0; m < 8; ++m)
#pragma unroll
        for (int n = 0; n < 4; ++n) acc[m][n] = zero4;
    float lp = 0.f;

    uint4 vbA[4], vbB[4];
#pragma unroll
    for (int n = 0; n < 4; ++n) vbA[n] = *(const uint4*)(bp[n]);

#define Q_GEN_P(JB, SIDE)                                                    \
    {                                                                        \
        unsigned pk4[4];                                                     \
        _Pragma("unroll") for (int i = 0; i < 8; i += 2) {                   \
            int j = (JB) + jq * 8 + i;                                       \
            f32x4 n0 = nsrc[j], n1 = nsrc[j + 1];                            \
            float s0 = fmaf(m2x, n0.x, fmaf(m2y, n0.y, fmaf(m2z, n0.z, q2 + n0.w))); \
            float s1 = fmaf(m2x, n1.x, fmaf(m2y, n1.y, fmaf(m2z, n1.z, q2 + n1.w))); \
            s0 = fmaxf(s0, 1e-12f); s1 = fmaxf(s1, 1e-12f);                  \
            float w0 = __builtin_amdgcn_exp2f(__builtin_amdgcn_sqrtf(s0) * -1.44269504f); \
            float w1 = __builtin_amdgcn_exp2f(__builtin_amdgcn_sqrtf(s1) * -1.44269504f); \
            unsigned u = pk_bf16(w0, w1);                                    \
            lp += bits_to_f(u << 16) + bits_to_f(u & 0xffff0000u);           \
            pk4[i >> 1] = u;                                                 \
        }                                                                    \
        *(uint4*)(&pbuf[SIDE][r * PSTR + jq * 8]) =                          \
            make_uint4(pk4[0], pk4[1], pk4[2], pk4[3]);                      \
    }

#define Q_MFMA(VB, SIDE)                                                     \
    {                                                                        \
        _Pragma("unroll") for (int m = 0; m < 8; ++m) {                      \
            bf16x8 a = *(const bf16x8*)(&pbuf[SIDE][(m * 16 + col) * PSTR + quad * 8]); \
            _Pragma("unroll") for (int n = 0; n < 4; ++n)                    \
                acc[m][n] = __builtin_amdgcn_mfma_f32_16x16x32_bf16(         \
                    a, as_bf16x8(VB[n]), acc[m][n], 0, 0, 0);                \
        }                                                                    \
    }

#define Q_BODY(CUR, NXT, SIDE, JNXT)                                         \
    {                                                                        \
        _Pragma("unroll") for (int n = 0; n < 4; ++n) {                      \
            NXT[n] = *(const uint4*)(bp[n] + BK);                            \
            bp[n] += BK;                                                     \
        }                                                                    \
        Q_GEN_P(JNXT, SIDE ^ 1)                                              \
        Q_MFMA(CUR, SIDE)                                                    \
        wg_barrier();                                                        \
    }

    Q_GEN_P(0, 0)
    wg_barrier();

    int jn = BK;
    for (int kt = 0; kt < 254; kt += 2) {
        Q_BODY(vbA, vbB, 0, jn) jn += BK;
        Q_BODY(vbB, vbA, 1, jn) jn += BK;
    }
    Q_BODY(vbA, vbB, 0, jn)   // kt = 254: prefetch V(255), P(255)->pbuf[1]
    Q_MFMA(vbB, 1)            // kt = 255
#undef Q_BODY
#undef Q_MFMA
#undef Q_GEN_P

    redl[t] = lp;
    __syncthreads();
    if (t < BM) lbuf[t] = redl[t] + redl[t + 128] + redl[t + 256] + redl[t + 384];
    __syncthreads();

#pragma unroll
    for (int m = 0; m < 8; ++m) {
        f32x4 l4 = *(const f32x4*)(lbuf + m * 16 + quad * 4);
        f32x4 inv4 = {1.0f / l4.x, 1.0f / l4.y, 1.0f / l4.z, 1.0f / l4.w};
        int qg = qb + m * 16 + quad * 4;
#pragma unroll
        for (int n = 0; n < 4; ++n) {
            int fg = wv * 64 + n * 16 + col;
            out[(size_t)(qg + 0) * F_DIM + fg] = acc[m][n].x * inv4.x;
            out[(size_t)(qg + 1) * F_DIM + fg] = acc[m][n].y * inv4.y;
            out[(size_t)(qg + 2) * F_DIM + fg] = acc[m][n].z * inv4.z;
            out[(size_t)(qg + 3) * F_DIM + fg] = acc[m][n].w * inv4.w;
        }
    }
}

// ---------------------------------------------------------------------------
// Workspace layout (bytes):
//   featT : [0,        8388608)   512x8192 bf16
//   memT  : [8388608, 16777216)   512x8192 bf16
//   npe4  : [16777216,16908288)   8192x4 fp32 (x,y,z,|npe|^2)
//   pn4   : [16908288,17039360)
//   en4   : [17039360,17170432)
//   pos4  : [17170432,17301504)
// ---------------------------------------------------------------------------
extern "C" void kernel_launch(void* const* d_in, const int* in_sizes, int n_in,
                              void* d_out, int out_size, void* d_ws, size_t ws_size,
                              hipStream_t stream) {
    const float* features  = (const float*)d_in[0];
    const float* positions = (const float*)d_in[1];
    const float* qpos      = (const float*)d_in[2];
    const float* pemb      = (const float*)d_in[3];
    float* out = (float*)d_out;
    char* ws = (char*)d_ws;

    unsigned short* featT = (unsigned short*)(ws);
    unsigned short* memT  = (unsigned short*)(ws + 8388608);
    float* npe4 = (float*)(ws + 16777216);
    float* pn4  = (float*)(ws + 16908288);
    float* en4  = (float*)(ws + 17039360);
    float* pos4 = (float*)(ws + 17170432);

    hipLaunchKernelGGL(prep_kernel, dim3(M_SZ / 256), dim3(256), 0, stream,
                       positions, pemb, pn4, en4, pos4);
    hipLaunchKernelGGL(transpose_kernel, dim3(M_SZ / 64, F_DIM / 64), dim3(256), 0, stream,
                       features, featT);
    hipLaunchKernelGGL(build_memory_kernel, dim3((M_SZ / 128) * 4), dim3(512), 0, stream,
                       pn4, en4, pos4, featT, memT, npe4);
    hipLaunchKernelGGL(query_kernel, dim3(N_Q / 128), dim3(512), 0, stream,
                       qpos, npe4, memT, out);
}